// Round 3
// baseline (266.952 us; speedup 1.0000x reference)
//
#include <hip/hip_runtime.h>

#define M_Q 50000
#define N_S 50000
#define H_N 32
#define K_P 15
#define C_IN 128
#define C_OUT 128
#define QB 32      // queries per block
#define AP 136     // padded A row length in bf16 elems

typedef __attribute__((ext_vector_type(8))) short s8v;   // 8 bf16 MFMA A/B frag
typedef __attribute__((ext_vector_type(4))) float f4v;   // MFMA C/D frag
typedef __attribute__((ext_vector_type(4))) float fl4;

static __device__ __forceinline__ unsigned f2bf_bits(float x) {
    union { float f; unsigned u; } v; v.f = x;
    return (v.u + 0x7fffu + ((v.u >> 16) & 1u)) >> 16;
}

// ---- pre-pass: W[k][c][d] fp32 -> Wt[k][d][c] bf16 ----
__global__ __launch_bounds__(256) void wcvt_kernel(const float* __restrict__ W,
                                                   unsigned short* __restrict__ Wt) {
    int i = blockIdx.x * 256 + threadIdx.x;
    if (i >= K_P * C_IN * C_OUT) return;
    int c = i & 127, d = (i >> 7) & 127, k = i >> 14;
    Wt[i] = (unsigned short)f2bf_bits(W[((size_t)k * 128 + c) * 128 + d]);
}

// ---- main: one (k, qtile) per block; no k-loop, 2 barriers total ----
// blockIdx.x = k (0..14), blockIdx.y = qtile (0..1562)
template <typename IT>
__global__ __launch_bounds__(256, 4) void kpconv_split(
    const float* __restrict__ q_pts,
    const float* __restrict__ s_pts,
    const float* __restrict__ s_feats,
    const IT* __restrict__ inds,
    const float* __restrict__ kernel_points,
    const unsigned short* __restrict__ Wt,   // bf16 bits, [K][D][C]
    float* __restrict__ out)                 // pre-zeroed; atomicAdd scatter
{
    __shared__ float s_q[QB * 3];
    __shared__ float s_w[QB][H_N];           // per-(q,h) weight for THIS k
    __shared__ int s_idx[QB][H_N];
    __shared__ unsigned s_hm[QB];            // active-h bitmask per q
    __shared__ unsigned short s_A[QB][AP];   // A_k tile, bf16 bits
    __shared__ int s_any;

    const int t = threadIdx.x;
    const int k = blockIdx.x;
    const int qbase = blockIdx.y * QB;

    const float kx = kernel_points[k * 3 + 0];
    const float ky = kernel_points[k * 3 + 1];
    const float kz = kernel_points[k * 3 + 2];

    if (t == 0) s_any = 0;
    if (t < QB * 3) {
        int g = qbase * 3 + t;
        s_q[t] = (g < M_Q * 3) ? q_pts[g] : 0.0f;
    }
    __syncthreads();

    // ---- phase 1: geometry for one k; hmask via wave ballot ----
    const int lane = t & 63;
    #pragma unroll
    for (int it = 0; it < 4; ++it) {
        const int task = it * 256 + t;           // = (qpair base)*32 + lane layout
        const int q = task >> 5, h = task & 31;
        const int qg = qbase + q;
        float w = 0.0f;
        int i32 = 0;
        if (qg < M_Q) {
            long long idx = (long long)inds[(size_t)qg * H_N + h];
            if ((unsigned long long)idx < (unsigned long long)N_S) {
                i32 = (int)idx;
                const float rx = s_pts[i32 * 3 + 0] - s_q[q * 3 + 0];
                const float ry = s_pts[i32 * 3 + 1] - s_q[q * 3 + 1];
                const float rz = s_pts[i32 * 3 + 2] - s_q[q * 3 + 2];
                const float dx = rx - kx, dy = ry - ky, dz = rz - kz;
                const float d2 = dx * dx + dy * dy + dz * dz;
                w = fmaxf(1.0f - sqrtf(d2), 0.0f);   // SIGMA = 1
            }
        }
        s_w[q][h] = w;
        s_idx[q][h] = i32;
        unsigned long long b = __ballot(w > 0.0f);
        if (lane == 0) {
            s_hm[q] = (unsigned)(b & 0xffffffffull);
            if ((unsigned)(b & 0xffffffffull)) atomicOr(&s_any, 1);
        } else if (lane == 32) {
            s_hm[q] = (unsigned)(b >> 32);
            if ((unsigned)(b >> 32)) atomicOr(&s_any, 1);
        }
    }
    __syncthreads();

    if (!s_any) return;   // out pre-zeroed; nothing to add

    // ---- phase 2: build A (32x128 bf16) with exact zero-skip ----
    const int qs = t >> 3, sub = t & 7, c0 = sub * 16;
    {
        float v[16];
        #pragma unroll
        for (int j = 0; j < 16; ++j) v[j] = 0.0f;
        unsigned hm = s_hm[qs];
        while (hm) {
            const int h = __builtin_ctz(hm); hm &= hm - 1;
            const float w = s_w[qs][h];
            const fl4* fp = (const fl4*)(s_feats + (size_t)s_idx[qs][h] * C_IN + c0);
            #pragma unroll
            for (int j4 = 0; j4 < 4; ++j4) {
                const fl4 f = fp[j4];
                v[j4 * 4 + 0] = fmaf(w, f.x, v[j4 * 4 + 0]);
                v[j4 * 4 + 1] = fmaf(w, f.y, v[j4 * 4 + 1]);
                v[j4 * 4 + 2] = fmaf(w, f.z, v[j4 * 4 + 2]);
                v[j4 * 4 + 3] = fmaf(w, f.w, v[j4 * 4 + 3]);
            }
        }
        #pragma unroll
        for (int j2 = 0; j2 < 8; ++j2) {
            const unsigned lo = f2bf_bits(v[2 * j2 + 0]);
            const unsigned hi = f2bf_bits(v[2 * j2 + 1]);
            *(unsigned*)&s_A[qs][c0 + 2 * j2] = lo | (hi << 16);
        }
    }
    __syncthreads();

    // ---- phase 3: GEMM  out_tile += A (32x128) * Wt_k^T (128x128) ----
    const int wave = t >> 6;
    const int quad = lane >> 4, l15 = lane & 15;
    const f4v zf = {0.0f, 0.0f, 0.0f, 0.0f};
    f4v acc[2][2];
    acc[0][0] = zf; acc[0][1] = zf; acc[1][0] = zf; acc[1][1] = zf;

    const unsigned short* Wk = Wt + (size_t)k * C_IN * C_OUT;
    #pragma unroll
    for (int kk = 0; kk < 4; ++kk) {
        const int coff = kk * 32 + quad * 8;
        const s8v a0 = *(const s8v*)&s_A[l15][coff];
        const s8v a1 = *(const s8v*)&s_A[16 + l15][coff];
        const s8v b0 = *(const s8v*)(Wk + (size_t)(wave * 32 + l15) * C_IN + coff);
        const s8v b1 = *(const s8v*)(Wk + (size_t)(wave * 32 + 16 + l15) * C_IN + coff);
        acc[0][0] = __builtin_amdgcn_mfma_f32_16x16x32_bf16(a0, b0, acc[0][0], 0, 0, 0);
        acc[1][0] = __builtin_amdgcn_mfma_f32_16x16x32_bf16(a1, b0, acc[1][0], 0, 0, 0);
        acc[0][1] = __builtin_amdgcn_mfma_f32_16x16x32_bf16(a0, b1, acc[0][1], 0, 0, 0);
        acc[1][1] = __builtin_amdgcn_mfma_f32_16x16x32_bf16(a1, b1, acc[1][1], 0, 0, 0);
    }

    // ---- epilogue: scatter-add active rows only ----
    // C/D layout: col = lane&15, row = (lane>>4)*4 + reg
    #pragma unroll
    for (int mt = 0; mt < 2; ++mt) {
        #pragma unroll
        for (int r = 0; r < 4; ++r) {
            const int row = mt * 16 + quad * 4 + r;
            const int qg = qbase + row;
            if (s_hm[row] && qg < M_Q) {
                float* op = out + (size_t)qg * C_OUT + wave * 32;
                atomicAdd(op + l15,      acc[mt][0][r]);
                atomicAdd(op + 16 + l15, acc[mt][1][r]);
            }
        }
    }
}

extern "C" void kernel_launch(void* const* d_in, const int* in_sizes, int n_in,
                              void* d_out, int out_size, void* d_ws, size_t ws_size,
                              hipStream_t stream) {
    const float* q_pts         = (const float*)d_in[0];
    const float* s_pts         = (const float*)d_in[1];
    const float* s_feats       = (const float*)d_in[2];
    const float* kernel_points = (const float*)d_in[4];
    const float* weights       = (const float*)d_in[5];
    float* out = (float*)d_out;
    const bool i64 = (in_sizes[3] == 2 * M_Q * H_N);
    const size_t wt_bytes = (size_t)K_P * C_IN * C_OUT * sizeof(unsigned short);

    // W -> bf16 transposed (d_ws)
    unsigned short* Wt = (unsigned short*)d_ws;
    wcvt_kernel<<<(K_P * C_IN * C_OUT + 255) / 256, 256, 0, stream>>>(weights, Wt);
    // zero output (scatter-add target)
    hipMemsetAsync(d_out, 0, (size_t)out_size * sizeof(float), stream);

    dim3 grid(K_P, (M_Q + QB - 1) / QB), block(256);
    (void)wt_bytes; (void)ws_size;
    if (i64)
        kpconv_split<long long><<<grid, block, 0, stream>>>(
            q_pts, s_pts, s_feats, (const long long*)d_in[3], kernel_points, Wt, out);
    else
        kpconv_split<int><<<grid, block, 0, stream>>>(
            q_pts, s_pts, s_feats, (const int*)d_in[3], kernel_points, Wt, out);
}